// Round 3
// baseline (346.162 us; speedup 1.0000x reference)
//
#include <hip/hip_runtime.h>

#define DIM 768
#define HEADS 12
#define HDIM 64
#define B_ 8
#define N_ 1024
#define EPS 1e-5f

typedef __bf16 bf16x8 __attribute__((ext_vector_type(8)));
typedef float  f32x4  __attribute__((ext_vector_type(4)));

using u16 = unsigned short;
using u32 = unsigned int;

static __device__ __forceinline__ u16 f2b_rne(float f){
    u32 u = __float_as_uint(f);
    u += 0x7fffu + ((u >> 16) & 1u);
    return (u16)(u >> 16);
}

// -------------------- cast fp32 -> bf16, 8 elems/thread --------------------
__global__ __launch_bounds__(256) void cast_bf16_kernel(
    const float* __restrict__ in, u16* __restrict__ out, int n8)
{
    int i = blockIdx.x * 256 + threadIdx.x;
    if (i >= n8) return;
    const float4* p = (const float4*)in;
    float4 a = p[2*i], b = p[2*i+1];
    uint4 r;
    r.x = (u32)f2b_rne(a.x) | ((u32)f2b_rne(a.y) << 16);
    r.y = (u32)f2b_rne(a.z) | ((u32)f2b_rne(a.w) << 16);
    r.z = (u32)f2b_rne(b.x) | ((u32)f2b_rne(b.y) << 16);
    r.w = (u32)f2b_rne(b.z) | ((u32)f2b_rne(b.w) << 16);
    ((uint4*)out)[i] = r;
}

// -------------------- Kernel 1: QKV GEMM (bf16 MFMA) + bias + fused LN --------------------
// C = xb[8192][768] @ wb[2304][768]^T. 128x128 tile, 4 waves 2x2, BK=64.
// Wave tile 64x64 == one head slice -> in-register LN via shfl.
// Q,K -> [B][H][N][D]; V -> transposed VT[B][H][D][N].
__global__ __launch_bounds__(256) void qkv_gemm_ln(
    const u16* __restrict__ xb, const u16* __restrict__ wb,
    const float* __restrict__ bias,
    const float* __restrict__ qn_w, const float* __restrict__ qn_b,
    const float* __restrict__ kn_w, const float* __restrict__ kn_b,
    u16* __restrict__ Q, u16* __restrict__ K, u16* __restrict__ VT)
{
    __shared__ __align__(16) unsigned char Asl[128*144];   // [128 rows][72 bf16] padded
    __shared__ __align__(16) unsigned char Bsl[128*144];
    const int t = threadIdx.x;
    const int lane = t & 63, wid = t >> 6;
    const int wr = wid >> 1, wc = wid & 1;
    const int l15 = lane & 15, l4 = lane >> 4;
    const int col0 = blockIdx.x * 128, row0 = blockIdx.y * 128;

    f32x4 acc[4][4];
    #pragma unroll
    for (int m = 0; m < 4; ++m)
        #pragma unroll
        for (int n = 0; n < 4; ++n) acc[m][n] = f32x4{0.f,0.f,0.f,0.f};

    for (int k0 = 0; k0 < DIM; k0 += 64) {
        uint4 ra[4], rb[4];
        #pragma unroll
        for (int p = 0; p < 4; ++p) {
            int idx = p*256 + t;
            int r = idx >> 3, cg = idx & 7;
            ra[p] = *(const uint4*)((const unsigned char*)xb + (size_t)(row0+r)*1536 + k0*2 + cg*16);
            rb[p] = *(const uint4*)((const unsigned char*)wb + (size_t)(col0+r)*1536 + k0*2 + cg*16);
        }
        __syncthreads();
        #pragma unroll
        for (int p = 0; p < 4; ++p) {
            int idx = p*256 + t;
            int r = idx >> 3, cg = idx & 7;
            *(uint4*)(Asl + r*144 + cg*16) = ra[p];
            *(uint4*)(Bsl + r*144 + cg*16) = rb[p];
        }
        __syncthreads();
        #pragma unroll
        for (int s = 0; s < 2; ++s) {
            bf16x8 af[4], bfr[4];
            #pragma unroll
            for (int m = 0; m < 4; ++m)
                af[m] = *(const bf16x8*)(Asl + (wr*64 + m*16 + l15)*144 + l4*16 + s*64);
            #pragma unroll
            for (int n = 0; n < 4; ++n)
                bfr[n] = *(const bf16x8*)(Bsl + (wc*64 + n*16 + l15)*144 + l4*16 + s*64);
            #pragma unroll
            for (int m = 0; m < 4; ++m)
                #pragma unroll
                for (int n = 0; n < 4; ++n)
                    acc[m][n] = __builtin_amdgcn_mfma_f32_16x16x32_bf16(af[m], bfr[n], acc[m][n], 0, 0, 0);
        }
    }

    // ---- epilogue: bias, LN (q,k), scatter ----
    const int cg0 = col0 + wc*64;          // global col of wave tile; head-aligned
    const int which = cg0 / DIM;           // 0=q 1=k 2=v
    const int h = (cg0 % DIM) / HDIM;

    float bias_v[4];
    #pragma unroll
    for (int n = 0; n < 4; ++n) bias_v[n] = bias[cg0 + n*16 + l15];
    #pragma unroll
    for (int m = 0; m < 4; ++m)
        #pragma unroll
        for (int n = 0; n < 4; ++n)
            #pragma unroll
            for (int r = 0; r < 4; ++r) acc[m][n][r] += bias_v[n];

    if (which < 2) {
        const float* lwp = (which == 0) ? qn_w : kn_w;
        const float* lbp = (which == 0) ? qn_b : kn_b;
        float lw_v[4], lb_v[4];
        #pragma unroll
        for (int n = 0; n < 4; ++n) { lw_v[n] = lwp[n*16 + l15]; lb_v[n] = lbp[n*16 + l15]; }

        #pragma unroll
        for (int m = 0; m < 4; ++m)
            #pragma unroll
            for (int r = 0; r < 4; ++r) {
                float s = 0.f, s2 = 0.f;
                #pragma unroll
                for (int n = 0; n < 4; ++n) { float v = acc[m][n][r]; s += v; s2 += v*v; }
                #pragma unroll
                for (int off = 1; off < 16; off <<= 1) {
                    s  += __shfl_xor(s,  off, 64);
                    s2 += __shfl_xor(s2, off, 64);
                }
                float mu  = s * (1.f/64.f);
                float var = s2 * (1.f/64.f) - mu*mu;
                float rs  = rsqrtf(var + EPS);
                #pragma unroll
                for (int n = 0; n < 4; ++n)
                    acc[m][n][r] = (acc[m][n][r] - mu) * rs * lw_v[n] + lb_v[n];
            }

        u16* dst = (which == 0) ? Q : K;
        #pragma unroll
        for (int m = 0; m < 4; ++m)
            #pragma unroll
            for (int r = 0; r < 4; ++r) {
                int rg = row0 + wr*64 + m*16 + l4*4 + r;
                size_t bhq = (size_t)((rg >> 10) * HEADS + h);
                int nn = rg & 1023;
                #pragma unroll
                for (int n = 0; n < 4; ++n)
                    dst[(bhq * N_ + nn) * HDIM + n*16 + l15] = f2b_rne(acc[m][n][r]);
            }
    } else {
        #pragma unroll
        for (int m = 0; m < 4; ++m)
            #pragma unroll
            for (int r = 0; r < 4; ++r) {
                int rg = row0 + wr*64 + m*16 + l4*4 + r;
                size_t bhq = (size_t)((rg >> 10) * HEADS + h);
                int nn = rg & 1023;
                #pragma unroll
                for (int n = 0; n < 4; ++n)
                    VT[(bhq * HDIM + n*16 + l15) * N_ + nn] = f2b_rne(acc[m][n][r]);
            }
    }
}

// -------------------- Kernel 2: flash attention (bf16 MFMA) --------------------
// Block: one (b,h), 64 queries. 4 waves x 16 q-rows. KV tiles of 64.
__global__ __launch_bounds__(256) void attn_mfma(
    const u16* __restrict__ Q, const u16* __restrict__ K,
    const u16* __restrict__ VT, u16* __restrict__ A)
{
    __shared__ __align__(16) unsigned char Ks[64*144];     // [64 kv][72 bf16]
    __shared__ __align__(16) unsigned char Vs[64*144];     // [64 d ][72 bf16] (VT tile)
    __shared__ __align__(16) unsigned char Ps[4*16*144];   // per-wave [16 q][72 bf16]
    const int t = threadIdx.x, lane = t & 63, w = t >> 6;
    const int l15 = lane & 15, l4 = lane >> 4;
    const int qt = blockIdx.x, bh = blockIdx.y;
    const size_t base = (size_t)bh * (N_ * HDIM);          // element offset

    bf16x8 qa[2];
    {
        const unsigned char* qb = (const unsigned char*)(Q + base + (size_t)(qt*64 + w*16 + l15) * HDIM);
        qa[0] = *(const bf16x8*)(qb + l4*16);
        qa[1] = *(const bf16x8*)(qb + l4*16 + 64);
    }

    float m_run[4], l_run[4];
    #pragma unroll
    for (int r = 0; r < 4; ++r) { m_run[r] = -1e30f; l_run[r] = 0.f; }
    f32x4 o[4];
    #pragma unroll
    for (int n = 0; n < 4; ++n) o[n] = f32x4{0.f,0.f,0.f,0.f};

    unsigned char* Pw = Ps + w*2304;

    for (int kt = 0; kt < 16; ++kt) {
        uint4 rk[2], rv[2];
        #pragma unroll
        for (int p = 0; p < 2; ++p) {
            int idx = p*256 + t;
            int r = idx >> 3, cg = idx & 7;
            rk[p] = *(const uint4*)((const unsigned char*)K  + base*2 + kt*8192 + r*128 + cg*16);
            rv[p] = *(const uint4*)((const unsigned char*)VT + base*2 + (size_t)r*2048 + kt*128 + cg*16);
        }
        __syncthreads();   // prior tile's LDS reads complete
        #pragma unroll
        for (int p = 0; p < 2; ++p) {
            int idx = p*256 + t;
            int r = idx >> 3, cg = idx & 7;
            *(uint4*)(Ks + r*144 + cg*16) = rk[p];
            *(uint4*)(Vs + r*144 + cg*16) = rv[p];
        }
        __syncthreads();

        // S = Q K^T : C rows=(l4*4+r)=q, cols=(n*16+l15)=kv
        f32x4 sv[4];
        #pragma unroll
        for (int n = 0; n < 4; ++n) {
            sv[n] = f32x4{0.f,0.f,0.f,0.f};
            #pragma unroll
            for (int s = 0; s < 2; ++s) {
                bf16x8 kb = *(const bf16x8*)(Ks + (n*16 + l15)*144 + l4*16 + s*64);
                sv[n] = __builtin_amdgcn_mfma_f32_16x16x32_bf16(qa[s], kb, sv[n], 0, 0, 0);
            }
        }
        #pragma unroll
        for (int n = 0; n < 4; ++n)
            #pragma unroll
            for (int r = 0; r < 4; ++r) sv[n][r] *= 0.125f;

        // online softmax over kv (in-lane n + shfl over lane bits 0-3)
        float mx[4];
        #pragma unroll
        for (int r = 0; r < 4; ++r)
            mx[r] = fmaxf(fmaxf(sv[0][r], sv[1][r]), fmaxf(sv[2][r], sv[3][r]));
        #pragma unroll
        for (int off = 1; off < 16; off <<= 1)
            #pragma unroll
            for (int r = 0; r < 4; ++r) mx[r] = fmaxf(mx[r], __shfl_xor(mx[r], off, 64));

        float newm[4], fac[4], rs[4];
        #pragma unroll
        for (int r = 0; r < 4; ++r) {
            newm[r] = fmaxf(m_run[r], mx[r]);
            fac[r]  = __expf(m_run[r] - newm[r]);
            rs[r]   = 0.f;
        }
        #pragma unroll
        for (int n = 0; n < 4; ++n)
            #pragma unroll
            for (int r = 0; r < 4; ++r) {
                float p = __expf(sv[n][r] - newm[r]);
                rs[r] += p;
                *(u16*)(Pw + (l4*4 + r)*144 + (n*16 + l15)*2) = f2b_rne(p);
            }
        #pragma unroll
        for (int off = 1; off < 16; off <<= 1)
            #pragma unroll
            for (int r = 0; r < 4; ++r) rs[r] += __shfl_xor(rs[r], off, 64);
        #pragma unroll
        for (int r = 0; r < 4; ++r) {
            l_run[r] = l_run[r] * fac[r] + rs[r];
            m_run[r] = newm[r];
        }
        #pragma unroll
        for (int n = 0; n < 4; ++n)
            #pragma unroll
            for (int r = 0; r < 4; ++r) o[n][r] *= fac[r];

        // O += P V : A-frag rows=l15 (q), k=kv ; B-frag from VT rows=d
        bf16x8 pa0 = *(const bf16x8*)(Pw + l15*144 + l4*16);
        bf16x8 pa1 = *(const bf16x8*)(Pw + l15*144 + l4*16 + 64);
        #pragma unroll
        for (int n = 0; n < 4; ++n) {
            bf16x8 vb0 = *(const bf16x8*)(Vs + (n*16 + l15)*144 + l4*16);
            o[n] = __builtin_amdgcn_mfma_f32_16x16x32_bf16(pa0, vb0, o[n], 0, 0, 0);
            bf16x8 vb1 = *(const bf16x8*)(Vs + (n*16 + l15)*144 + l4*16 + 64);
            o[n] = __builtin_amdgcn_mfma_f32_16x16x32_bf16(pa1, vb1, o[n], 0, 0, 0);
        }
    }

    const int b = bh / HEADS, h = bh % HEADS;
    #pragma unroll
    for (int r = 0; r < 4; ++r) {
        float inv = 1.f / l_run[r];
        int n_glob = qt*64 + w*16 + l4*4 + r;
        #pragma unroll
        for (int n = 0; n < 4; ++n)
            A[(((size_t)b * N_ + n_glob) * HEADS + h) * HDIM + n*16 + l15] = f2b_rne(o[n][r] * inv);
    }
}

// -------------------- Kernel 3: output projection (bf16 MFMA, fp32 out) --------------------
__global__ __launch_bounds__(256) void proj_gemm(
    const u16* __restrict__ Ab, const u16* __restrict__ wb,
    const float* __restrict__ bias, float* __restrict__ out)
{
    __shared__ __align__(16) unsigned char Asl[128*144];
    __shared__ __align__(16) unsigned char Bsl[128*144];
    const int t = threadIdx.x;
    const int lane = t & 63, wid = t >> 6;
    const int wr = wid >> 1, wc = wid & 1;
    const int l15 = lane & 15, l4 = lane >> 4;
    const int col0 = blockIdx.x * 128, row0 = blockIdx.y * 128;

    f32x4 acc[4][4];
    #pragma unroll
    for (int m = 0; m < 4; ++m)
        #pragma unroll
        for (int n = 0; n < 4; ++n) acc[m][n] = f32x4{0.f,0.f,0.f,0.f};

    for (int k0 = 0; k0 < DIM; k0 += 64) {
        uint4 ra[4], rb[4];
        #pragma unroll
        for (int p = 0; p < 4; ++p) {
            int idx = p*256 + t;
            int r = idx >> 3, cg = idx & 7;
            ra[p] = *(const uint4*)((const unsigned char*)Ab + (size_t)(row0+r)*1536 + k0*2 + cg*16);
            rb[p] = *(const uint4*)((const unsigned char*)wb + (size_t)(col0+r)*1536 + k0*2 + cg*16);
        }
        __syncthreads();
        #pragma unroll
        for (int p = 0; p < 4; ++p) {
            int idx = p*256 + t;
            int r = idx >> 3, cg = idx & 7;
            *(uint4*)(Asl + r*144 + cg*16) = ra[p];
            *(uint4*)(Bsl + r*144 + cg*16) = rb[p];
        }
        __syncthreads();
        #pragma unroll
        for (int s = 0; s < 2; ++s) {
            bf16x8 af[4], bfr[4];
            #pragma unroll
            for (int m = 0; m < 4; ++m)
                af[m] = *(const bf16x8*)(Asl + (wr*64 + m*16 + l15)*144 + l4*16 + s*64);
            #pragma unroll
            for (int n = 0; n < 4; ++n)
                bfr[n] = *(const bf16x8*)(Bsl + (wc*64 + n*16 + l15)*144 + l4*16 + s*64);
            #pragma unroll
            for (int m = 0; m < 4; ++m)
                #pragma unroll
                for (int n = 0; n < 4; ++n)
                    acc[m][n] = __builtin_amdgcn_mfma_f32_16x16x32_bf16(af[m], bfr[n], acc[m][n], 0, 0, 0);
        }
    }

    float bias_v[4];
    #pragma unroll
    for (int n = 0; n < 4; ++n) bias_v[n] = bias[col0 + wc*64 + n*16 + l15];
    #pragma unroll
    for (int m = 0; m < 4; ++m)
        #pragma unroll
        for (int r = 0; r < 4; ++r) {
            int rg = row0 + wr*64 + m*16 + l4*4 + r;
            #pragma unroll
            for (int n = 0; n < 4; ++n)
                out[(size_t)rg * DIM + col0 + wc*64 + n*16 + l15] = acc[m][n][r] + bias_v[n];
        }
}

extern "C" void kernel_launch(void* const* d_in, const int* in_sizes, int n_in,
                              void* d_out, int out_size, void* d_ws, size_t ws_size,
                              hipStream_t stream)
{
    const float* x      = (const float*)d_in[0];
    const float* qkv_w  = (const float*)d_in[1];
    const float* qkv_b  = (const float*)d_in[2];
    const float* qn_w   = (const float*)d_in[3];
    const float* qn_b   = (const float*)d_in[4];
    const float* kn_w   = (const float*)d_in[5];
    const float* kn_b   = (const float*)d_in[6];
    const float* proj_w = (const float*)d_in[7];
    const float* proj_b = (const float*)d_in[8];
    float* out = (float*)d_out;

    const size_t XE  = (size_t)B_ * N_ * DIM;   // 6291456
    const size_t QWE = (size_t)3 * DIM * DIM;   // 1769472
    const size_t PWE = (size_t)DIM * DIM;       // 589824

    u16* xb  = (u16*)d_ws;
    u16* qwb = xb  + XE;
    u16* pwb = qwb + QWE;
    u16* Qb  = pwb + PWE;
    u16* Kb  = Qb  + XE;
    u16* VTb = Kb  + XE;
    u16* Ab  = VTb + XE;    // total 67.6 MB

    cast_bf16_kernel<<<(int)((XE/8  + 255)/256), 256, 0, stream>>>(x,      xb,  (int)(XE/8));
    cast_bf16_kernel<<<(int)((QWE/8 + 255)/256), 256, 0, stream>>>(qkv_w,  qwb, (int)(QWE/8));
    cast_bf16_kernel<<<(int)((PWE/8 + 255)/256), 256, 0, stream>>>(proj_w, pwb, (int)(PWE/8));

    qkv_gemm_ln<<<dim3(18, 64), 256, 0, stream>>>(xb, qwb, qkv_b, qn_w, qn_b,
                                                  kn_w, kn_b, Qb, Kb, VTb);
    attn_mfma<<<dim3(16, 96), 256, 0, stream>>>(Qb, Kb, VTb, Ab);
    proj_gemm<<<dim3(6, 64), 256, 0, stream>>>(Ab, pwb, proj_b, out);
}

// Round 4
// 331.675 us; speedup vs baseline: 1.0437x; 1.0437x over previous
//
#include <hip/hip_runtime.h>

#define DIM 768
#define HEADS 12
#define HDIM 64
#define B_ 8
#define N_ 1024
#define EPS 1e-5f

typedef __bf16 bf16x8 __attribute__((ext_vector_type(8)));
typedef float  f32x4  __attribute__((ext_vector_type(4)));

using u16 = unsigned short;
using u32 = unsigned int;

static __device__ __forceinline__ u16 f2b_rne(float f){
    u32 u = __float_as_uint(f);
    u += 0x7fffu + ((u >> 16) & 1u);
    return (u16)(u >> 16);
}

// -------------------- cast fp32 -> bf16, 8 elems/thread --------------------
__global__ __launch_bounds__(256) void cast_bf16_kernel(
    const float* __restrict__ in, u16* __restrict__ out, int n8)
{
    int i = blockIdx.x * 256 + threadIdx.x;
    if (i >= n8) return;
    const float4* p = (const float4*)in;
    float4 a = p[2*i], b = p[2*i+1];
    uint4 r;
    r.x = (u32)f2b_rne(a.x) | ((u32)f2b_rne(a.y) << 16);
    r.y = (u32)f2b_rne(a.z) | ((u32)f2b_rne(a.w) << 16);
    r.z = (u32)f2b_rne(b.x) | ((u32)f2b_rne(b.y) << 16);
    r.w = (u32)f2b_rne(b.z) | ((u32)f2b_rne(b.w) << 16);
    ((uint4*)out)[i] = r;
}

// -------------------- Kernel 1: QKV GEMM (bf16 MFMA) + bias + fused LN --------------------
// C = xb[8192][768] @ wb[2304][768]^T. 128x128 tile, 4 waves 2x2, BK=64, pipelined.
// Q,K -> [B][H][N][D]; V -> VT[B][H][D][N] via LDS transpose (coalesced writes).
__global__ __launch_bounds__(256) void qkv_gemm_ln(
    const u16* __restrict__ xb, const u16* __restrict__ wb,
    const float* __restrict__ bias,
    const float* __restrict__ qn_w, const float* __restrict__ qn_b,
    const float* __restrict__ kn_w, const float* __restrict__ kn_b,
    u16* __restrict__ Q, u16* __restrict__ K, u16* __restrict__ VT)
{
    __shared__ __align__(16) unsigned char Asl[128*144];   // [128 rows][72 bf16] padded
    __shared__ __align__(16) unsigned char Bsl[128*144];
    const int t = threadIdx.x;
    const int lane = t & 63, wid = t >> 6;
    const int wr = wid >> 1, wc = wid & 1;
    const int l15 = lane & 15, l4 = lane >> 4;

    // XCD swizzle: grid 1152 = 8 * 144
    const int b0 = blockIdx.x;
    const int lg = (b0 & 7) * 144 + (b0 >> 3);
    const int col0 = (lg % 18) * 128, row0 = (lg / 18) * 128;

    f32x4 acc[4][4];
    #pragma unroll
    for (int m = 0; m < 4; ++m)
        #pragma unroll
        for (int n = 0; n < 4; ++n) acc[m][n] = f32x4{0.f,0.f,0.f,0.f};

    uint4 ra[4], rb[4];
    #pragma unroll
    for (int p = 0; p < 4; ++p) {
        int idx = p*256 + t;
        int r = idx >> 3, cg = idx & 7;
        ra[p] = *(const uint4*)((const unsigned char*)xb + (size_t)(row0+r)*1536 + cg*16);
        rb[p] = *(const uint4*)((const unsigned char*)wb + (size_t)(col0+r)*1536 + cg*16);
    }

    for (int k0 = 0; k0 < DIM; k0 += 64) {
        __syncthreads();   // previous tile's LDS reads complete
        #pragma unroll
        for (int p = 0; p < 4; ++p) {
            int idx = p*256 + t;
            int r = idx >> 3, cg = idx & 7;
            *(uint4*)(Asl + r*144 + cg*16) = ra[p];
            *(uint4*)(Bsl + r*144 + cg*16) = rb[p];
        }
        __syncthreads();
        if (k0 + 64 < DIM) {   // prefetch next tile; overlaps with MFMA below
            #pragma unroll
            for (int p = 0; p < 4; ++p) {
                int idx = p*256 + t;
                int r = idx >> 3, cg = idx & 7;
                ra[p] = *(const uint4*)((const unsigned char*)xb + (size_t)(row0+r)*1536 + (k0+64)*2 + cg*16);
                rb[p] = *(const uint4*)((const unsigned char*)wb + (size_t)(col0+r)*1536 + (k0+64)*2 + cg*16);
            }
        }
        #pragma unroll
        for (int s = 0; s < 2; ++s) {
            bf16x8 af[4], bfr[4];
            #pragma unroll
            for (int m = 0; m < 4; ++m)
                af[m] = *(const bf16x8*)(Asl + (wr*64 + m*16 + l15)*144 + l4*16 + s*64);
            #pragma unroll
            for (int n = 0; n < 4; ++n)
                bfr[n] = *(const bf16x8*)(Bsl + (wc*64 + n*16 + l15)*144 + l4*16 + s*64);
            #pragma unroll
            for (int m = 0; m < 4; ++m)
                #pragma unroll
                for (int n = 0; n < 4; ++n)
                    acc[m][n] = __builtin_amdgcn_mfma_f32_16x16x32_bf16(af[m], bfr[n], acc[m][n], 0, 0, 0);
        }
    }

    // ---- epilogue ----
    const int cg0 = col0 + wc*64;          // head-aligned; `which` uniform across block
    const int which = cg0 / DIM;           // 0=q 1=k 2=v
    const int h = (cg0 % DIM) / HDIM;

    float bias_v[4];
    #pragma unroll
    for (int n = 0; n < 4; ++n) bias_v[n] = bias[cg0 + n*16 + l15];
    #pragma unroll
    for (int m = 0; m < 4; ++m)
        #pragma unroll
        for (int n = 0; n < 4; ++n)
            #pragma unroll
            for (int r = 0; r < 4; ++r) acc[m][n][r] += bias_v[n];

    if (which < 2) {
        const float* lwp = (which == 0) ? qn_w : kn_w;
        const float* lbp = (which == 0) ? qn_b : kn_b;
        float lw_v[4], lb_v[4];
        #pragma unroll
        for (int n = 0; n < 4; ++n) { lw_v[n] = lwp[n*16 + l15]; lb_v[n] = lbp[n*16 + l15]; }

        #pragma unroll
        for (int m = 0; m < 4; ++m)
            #pragma unroll
            for (int r = 0; r < 4; ++r) {
                float s = 0.f, s2 = 0.f;
                #pragma unroll
                for (int n = 0; n < 4; ++n) { float v = acc[m][n][r]; s += v; s2 += v*v; }
                #pragma unroll
                for (int off = 1; off < 16; off <<= 1) {
                    s  += __shfl_xor(s,  off, 64);
                    s2 += __shfl_xor(s2, off, 64);
                }
                float mu  = s * (1.f/64.f);
                float var = s2 * (1.f/64.f) - mu*mu;
                float rs  = rsqrtf(var + EPS);
                #pragma unroll
                for (int n = 0; n < 4; ++n)
                    acc[m][n][r] = (acc[m][n][r] - mu) * rs * lw_v[n] + lb_v[n];
            }

        u16* dst = (which == 0) ? Q : K;
        #pragma unroll
        for (int m = 0; m < 4; ++m)
            #pragma unroll
            for (int r = 0; r < 4; ++r) {
                int rg = row0 + wr*64 + m*16 + l4*4 + r;
                size_t bhq = (size_t)((rg >> 10) * HEADS + h);
                int nn = rg & 1023;
                #pragma unroll
                for (int n = 0; n < 4; ++n)
                    dst[(bhq * N_ + nn) * HDIM + n*16 + l15] = f2b_rne(acc[m][n][r]);
            }
    } else {
        // V: transpose 64x64 wave tile through LDS -> coalesced 16B stores to VT
        __syncthreads();   // uniform across block (all waves are V); A/B LDS now dead
        unsigned char* Tw = (wid < 2 ? Asl : Bsl) + (wid & 1) * 8448;   // 64 rows x 132B
        #pragma unroll
        for (int n = 0; n < 4; ++n)
            #pragma unroll
            for (int m = 0; m < 4; ++m)
                #pragma unroll
                for (int r = 0; r < 4; ++r)
                    *(u16*)(Tw + (n*16 + l15)*132 + (m*16 + l4*4 + r)*2) = f2b_rne(acc[m][n][r]);

        const int tok0 = row0 + wr*64;
        const int b = tok0 >> 10, n0v = tok0 & 1023;
        const size_t bh = (size_t)(b * HEADS + h);
        #pragma unroll
        for (int i = 0; i < 8; ++i) {
            int d  = i*8 + (lane >> 3);
            int tk = (lane & 7) * 8;
            uint4 val = *(const uint4*)(Tw + d*132 + tk*2);
            *(uint4*)(VT + (bh * HDIM + d) * N_ + n0v + tk) = val;
        }
    }
}

// -------------------- Kernel 2: flash attention (bf16 MFMA, pipelined) --------------------
__global__ __launch_bounds__(256) void attn_mfma(
    const u16* __restrict__ Q, const u16* __restrict__ K,
    const u16* __restrict__ VT, u16* __restrict__ A)
{
    __shared__ __align__(16) unsigned char Ks[64*144];
    __shared__ __align__(16) unsigned char Vs[64*144];
    __shared__ __align__(16) unsigned char Ps[4*16*144];
    const int t = threadIdx.x, lane = t & 63, w = t >> 6;
    const int l15 = lane & 15, l4 = lane >> 4;

    // XCD swizzle: grid 1536 = 8 * 192; qt fastest within chunk -> KV reuse per XCD
    const int b0 = blockIdx.x;
    const int lg = (b0 & 7) * 192 + (b0 >> 3);
    const int qt = lg & 15, bh = lg >> 4;
    const size_t base = (size_t)bh * (N_ * HDIM);

    bf16x8 qa[2];
    {
        const unsigned char* qb = (const unsigned char*)(Q + base + (size_t)(qt*64 + w*16 + l15) * HDIM);
        qa[0] = *(const bf16x8*)(qb + l4*16);
        qa[1] = *(const bf16x8*)(qb + l4*16 + 64);
    }

    float m_run[4], l_run[4];
    #pragma unroll
    for (int r = 0; r < 4; ++r) { m_run[r] = -1e30f; l_run[r] = 0.f; }
    f32x4 o[4];
    #pragma unroll
    for (int n = 0; n < 4; ++n) o[n] = f32x4{0.f,0.f,0.f,0.f};

    unsigned char* Pw = Ps + w*2304;

    uint4 rk[2], rv[2];
    #pragma unroll
    for (int p = 0; p < 2; ++p) {
        int idx = p*256 + t;
        int r = idx >> 3, cg = idx & 7;
        rk[p] = *(const uint4*)((const unsigned char*)K  + base*2 + r*128 + cg*16);
        rv[p] = *(const uint4*)((const unsigned char*)VT + base*2 + (size_t)r*2048 + cg*16);
    }

    for (int kt = 0; kt < 16; ++kt) {
        __syncthreads();
        #pragma unroll
        for (int p = 0; p < 2; ++p) {
            int idx = p*256 + t;
            int r = idx >> 3, cg = idx & 7;
            *(uint4*)(Ks + r*144 + cg*16) = rk[p];
            *(uint4*)(Vs + r*144 + cg*16) = rv[p];
        }
        __syncthreads();
        if (kt < 15) {   // prefetch next KV tile; overlaps with compute below
            #pragma unroll
            for (int p = 0; p < 2; ++p) {
                int idx = p*256 + t;
                int r = idx >> 3, cg = idx & 7;
                rk[p] = *(const uint4*)((const unsigned char*)K  + base*2 + (kt+1)*8192 + r*128 + cg*16);
                rv[p] = *(const uint4*)((const unsigned char*)VT + base*2 + (size_t)r*2048 + (kt+1)*128 + cg*16);
            }
        }

        // S = Q K^T : rows=(l4*4+r)=q, cols=(n*16+l15)=kv
        f32x4 sv[4];
        #pragma unroll
        for (int n = 0; n < 4; ++n) {
            sv[n] = f32x4{0.f,0.f,0.f,0.f};
            #pragma unroll
            for (int s = 0; s < 2; ++s) {
                bf16x8 kb = *(const bf16x8*)(Ks + (n*16 + l15)*144 + l4*16 + s*64);
                sv[n] = __builtin_amdgcn_mfma_f32_16x16x32_bf16(qa[s], kb, sv[n], 0, 0, 0);
            }
        }
        #pragma unroll
        for (int n = 0; n < 4; ++n)
            #pragma unroll
            for (int r = 0; r < 4; ++r) sv[n][r] *= 0.125f;

        float mx[4];
        #pragma unroll
        for (int r = 0; r < 4; ++r)
            mx[r] = fmaxf(fmaxf(sv[0][r], sv[1][r]), fmaxf(sv[2][r], sv[3][r]));
        #pragma unroll
        for (int off = 1; off < 16; off <<= 1)
            #pragma unroll
            for (int r = 0; r < 4; ++r) mx[r] = fmaxf(mx[r], __shfl_xor(mx[r], off, 64));

        float newm[4], fac[4], rs[4];
        #pragma unroll
        for (int r = 0; r < 4; ++r) {
            newm[r] = fmaxf(m_run[r], mx[r]);
            fac[r]  = __expf(m_run[r] - newm[r]);
            rs[r]   = 0.f;
        }
        #pragma unroll
        for (int n = 0; n < 4; ++n)
            #pragma unroll
            for (int r = 0; r < 4; ++r) {
                float p = __expf(sv[n][r] - newm[r]);
                rs[r] += p;
                *(u16*)(Pw + (l4*4 + r)*144 + (n*16 + l15)*2) = f2b_rne(p);
            }
        #pragma unroll
        for (int off = 1; off < 16; off <<= 1)
            #pragma unroll
            for (int r = 0; r < 4; ++r) rs[r] += __shfl_xor(rs[r], off, 64);
        #pragma unroll
        for (int r = 0; r < 4; ++r) {
            l_run[r] = l_run[r] * fac[r] + rs[r];
            m_run[r] = newm[r];
        }
        #pragma unroll
        for (int n = 0; n < 4; ++n)
            #pragma unroll
            for (int r = 0; r < 4; ++r) o[n][r] *= fac[r];

        bf16x8 pa0 = *(const bf16x8*)(Pw + l15*144 + l4*16);
        bf16x8 pa1 = *(const bf16x8*)(Pw + l15*144 + l4*16 + 64);
        #pragma unroll
        for (int n = 0; n < 4; ++n) {
            bf16x8 vb0 = *(const bf16x8*)(Vs + (n*16 + l15)*144 + l4*16);
            o[n] = __builtin_amdgcn_mfma_f32_16x16x32_bf16(pa0, vb0, o[n], 0, 0, 0);
            bf16x8 vb1 = *(const bf16x8*)(Vs + (n*16 + l15)*144 + l4*16 + 64);
            o[n] = __builtin_amdgcn_mfma_f32_16x16x32_bf16(pa1, vb1, o[n], 0, 0, 0);
        }
    }

    const int b = bh / HEADS, h = bh % HEADS;
    #pragma unroll
    for (int r = 0; r < 4; ++r) {
        float inv = 1.f / l_run[r];
        int n_glob = qt*64 + w*16 + l4*4 + r;
        #pragma unroll
        for (int n = 0; n < 4; ++n)
            A[(((size_t)b * N_ + n_glob) * HEADS + h) * HDIM + n*16 + l15] = f2b_rne(o[n][r] * inv);
    }
}

// -------------------- Kernel 3: output projection (bf16 MFMA, fp32 out, pipelined) --------------------
__global__ __launch_bounds__(256) void proj_gemm(
    const u16* __restrict__ Ab, const u16* __restrict__ wb,
    const float* __restrict__ bias, float* __restrict__ out)
{
    __shared__ __align__(16) unsigned char Asl[128*144];
    __shared__ __align__(16) unsigned char Bsl[128*144];
    const int t = threadIdx.x;
    const int lane = t & 63, wid = t >> 6;
    const int wr = wid >> 1, wc = wid & 1;
    const int l15 = lane & 15, l4 = lane >> 4;

    // XCD swizzle: grid 384 = 8 * 48
    const int b0 = blockIdx.x;
    const int lg = (b0 & 7) * 48 + (b0 >> 3);
    const int col0 = (lg % 6) * 128, row0 = (lg / 6) * 128;

    f32x4 acc[4][4];
    #pragma unroll
    for (int m = 0; m < 4; ++m)
        #pragma unroll
        for (int n = 0; n < 4; ++n) acc[m][n] = f32x4{0.f,0.f,0.f,0.f};

    uint4 ra[4], rb[4];
    #pragma unroll
    for (int p = 0; p < 4; ++p) {
        int idx = p*256 + t;
        int r = idx >> 3, cg = idx & 7;
        ra[p] = *(const uint4*)((const unsigned char*)Ab + (size_t)(row0+r)*1536 + cg*16);
        rb[p] = *(const uint4*)((const unsigned char*)wb + (size_t)(col0+r)*1536 + cg*16);
    }

    for (int k0 = 0; k0 < DIM; k0 += 64) {
        __syncthreads();
        #pragma unroll
        for (int p = 0; p < 4; ++p) {
            int idx = p*256 + t;
            int r = idx >> 3, cg = idx & 7;
            *(uint4*)(Asl + r*144 + cg*16) = ra[p];
            *(uint4*)(Bsl + r*144 + cg*16) = rb[p];
        }
        __syncthreads();
        if (k0 + 64 < DIM) {
            #pragma unroll
            for (int p = 0; p < 4; ++p) {
                int idx = p*256 + t;
                int r = idx >> 3, cg = idx & 7;
                ra[p] = *(const uint4*)((const unsigned char*)Ab + (size_t)(row0+r)*1536 + (k0+64)*2 + cg*16);
                rb[p] = *(const uint4*)((const unsigned char*)wb + (size_t)(col0+r)*1536 + (k0+64)*2 + cg*16);
            }
        }
        #pragma unroll
        for (int s = 0; s < 2; ++s) {
            bf16x8 af[4], bfr[4];
            #pragma unroll
            for (int m = 0; m < 4; ++m)
                af[m] = *(const bf16x8*)(Asl + (wr*64 + m*16 + l15)*144 + l4*16 + s*64);
            #pragma unroll
            for (int n = 0; n < 4; ++n)
                bfr[n] = *(const bf16x8*)(Bsl + (wc*64 + n*16 + l15)*144 + l4*16 + s*64);
            #pragma unroll
            for (int m = 0; m < 4; ++m)
                #pragma unroll
                for (int n = 0; n < 4; ++n)
                    acc[m][n] = __builtin_amdgcn_mfma_f32_16x16x32_bf16(af[m], bfr[n], acc[m][n], 0, 0, 0);
        }
    }

    float bias_v[4];
    #pragma unroll
    for (int n = 0; n < 4; ++n) bias_v[n] = bias[col0 + wc*64 + n*16 + l15];
    #pragma unroll
    for (int m = 0; m < 4; ++m)
        #pragma unroll
        for (int r = 0; r < 4; ++r) {
            int rg = row0 + wr*64 + m*16 + l4*4 + r;
            #pragma unroll
            for (int n = 0; n < 4; ++n)
                out[(size_t)rg * DIM + col0 + wc*64 + n*16 + l15] = acc[m][n][r] + bias_v[n];
        }
}

extern "C" void kernel_launch(void* const* d_in, const int* in_sizes, int n_in,
                              void* d_out, int out_size, void* d_ws, size_t ws_size,
                              hipStream_t stream)
{
    const float* x      = (const float*)d_in[0];
    const float* qkv_w  = (const float*)d_in[1];
    const float* qkv_b  = (const float*)d_in[2];
    const float* qn_w   = (const float*)d_in[3];
    const float* qn_b   = (const float*)d_in[4];
    const float* kn_w   = (const float*)d_in[5];
    const float* kn_b   = (const float*)d_in[6];
    const float* proj_w = (const float*)d_in[7];
    const float* proj_b = (const float*)d_in[8];
    float* out = (float*)d_out;

    const size_t XE  = (size_t)B_ * N_ * DIM;   // 6291456
    const size_t QWE = (size_t)3 * DIM * DIM;   // 1769472
    const size_t PWE = (size_t)DIM * DIM;       // 589824

    u16* xb  = (u16*)d_ws;
    u16* qwb = xb  + XE;
    u16* pwb = qwb + QWE;
    u16* Qb  = pwb + PWE;
    u16* Kb  = Qb  + XE;
    u16* VTb = Kb  + XE;
    u16* Ab  = VTb + XE;    // total 67.6 MB

    cast_bf16_kernel<<<(int)((XE/8  + 255)/256), 256, 0, stream>>>(x,      xb,  (int)(XE/8));
    cast_bf16_kernel<<<(int)((QWE/8 + 255)/256), 256, 0, stream>>>(qkv_w,  qwb, (int)(QWE/8));
    cast_bf16_kernel<<<(int)((PWE/8 + 255)/256), 256, 0, stream>>>(proj_w, pwb, (int)(PWE/8));

    qkv_gemm_ln<<<dim3(1152), 256, 0, stream>>>(xb, qwb, qkv_b, qn_w, qn_b,
                                                kn_w, kn_b, Qb, Kb, VTb);
    attn_mfma<<<dim3(1536), 256, 0, stream>>>(Qb, Kb, VTb, Ab);
    proj_gemm<<<dim3(384), 256, 0, stream>>>(Ab, pwb, proj_b, out);
}